// Round 8
// baseline (171.198 us; speedup 1.0000x reference)
//
#include <hip/hip_runtime.h>

#define HID 64
#define N_GRAPHS_C 512
#define BSHIFT 8          // 256 nodes per coarse bucket
#define NBUCK_MAX 512
#define CAP 3264          // bucket capacity (mean 2560 + ~12 sigma)
#define EPB 4096          // edges per block in bin pass (245 blocks; 2048 was -3us worse, r6)
#define EPT (EPB / 512)   // edges per thread in bin pass (8)

typedef unsigned short u16;
typedef unsigned int u32;
typedef unsigned long long u64;

__device__ __forceinline__ float bf2f(u16 u) {
    union { u32 i; float f; } v; v.i = ((u32)u) << 16; return v.f;
}
__device__ __forceinline__ u16 f2bf(float f) {
    union { float f; u32 i; } v; v.f = f;
    u32 x = v.i;
    return (u16)((x + 0x7fffu + ((x >> 16) & 1u)) >> 16);  // RNE
}

__device__ __forceinline__ int lower_bound(const int* __restrict__ a, int n, int key) {
    int lo = 0, hi = n;
    while (lo < hi) {
        int mid = (lo + hi) >> 1;
        if (a[mid] < key) lo = mid + 1; else hi = mid;
    }
    return lo;
}

// ---------------- binning: packed u32 pairs, 512-thread blocks --------------
// pack = (local_dst << 17) | src   (local_dst < 256 -> 8 bits, src < 131072)
// gcursor pre-zeroed by hipMemsetAsync.

__global__ void bin_pairs(const int* __restrict__ src, const int* __restrict__ dst,
                          int* __restrict__ gcursor, u32* __restrict__ pairs,
                          int nE, int nbuck) {
    __shared__ int lh[NBUCK_MAX];
    __shared__ int lbase[NBUCK_MAX];
    int t = threadIdx.x;                       // 0..511
    lh[t] = 0;
    __syncthreads();
    int base = blockIdx.x * EPB;
    u32 pk[EPT]; int rj[EPT], bj[EPT];
    #pragma unroll
    for (int j = 0; j < EPT; ++j) {
        int e = base + j * 512 + t;
        if (e < nE) {
            int s = src[e], d = dst[e];
            bj[j] = d >> BSHIFT;
            pk[j] = ((u32)(d & 255) << 17) | (u32)s;
            rj[j] = atomicAdd(&lh[bj[j]], 1);
        } else {
            bj[j] = -1;
        }
    }
    __syncthreads();
    if (t < nbuck) lbase[t] = (lh[t] > 0) ? atomicAdd(&gcursor[t], lh[t]) : 0;
    __syncthreads();
    #pragma unroll
    for (int j = 0; j < EPT; ++j) {
        if (bj[j] >= 0) {
            int pos = bj[j] * CAP + lbase[bj[j]] + rj[j];
            pairs[pos] = pk[j];
        }
    }
}

// One block per bucket (512 thr): LDS histogram, LDS scan (first 256 thr) ->
// (beg,end) + dinv + xs, then LDS-cursor csr fill. Block 0 also computes
// gstart (one binary search per thread) and zeroes the A16 pad row.
__global__ void build_csr(const u32* __restrict__ pairs, const int* __restrict__ gcursor,
                          int* __restrict__ csr_src, int2* __restrict__ off2,
                          float* __restrict__ dinv, const float* __restrict__ x,
                          float4* __restrict__ xs, u16* __restrict__ A16,
                          const int* __restrict__ batch, int* __restrict__ gstart,
                          int nGraphs, int n) {
    __shared__ int hist[256];
    __shared__ int tmp[256];
    int t = threadIdx.x;                       // 0..511
    int b = blockIdx.x;
    int pbeg = b * CAP;
    int pend = pbeg + gcursor[b];
    if (t < 256) hist[t] = 0;
    if (b == 0 && t < 32) ((u32*)(A16 + (size_t)n * HID))[t] = 0;  // zero pad row
    if (b == 0) {                              // gstart: 513 searches, 1/thread
        for (int g = t; g <= nGraphs; g += 512)
            gstart[g] = lower_bound(batch, n, g);
    }
    __syncthreads();
    for (int i = pbeg + t; i < pend; i += 512)
        atomicAdd(&hist[pairs[i] >> 17], 1);
    __syncthreads();
    int v = 0;
    if (t < 256) { v = hist[t]; tmp[t] = v; }
    __syncthreads();
    for (int d = 1; d < 256; d <<= 1) {
        int add = (t >= d && t < 256) ? tmp[t - d] : 0;
        __syncthreads();
        if (t < 256) tmp[t] += add;
        __syncthreads();
    }
    if (t < 256) {
        int e = pbeg + tmp[t] - v;             // exclusive
        int node = (b << BSHIFT) + t;
        if (node < n) {
            float dv = rsqrtf((float)(v + 1));
            off2[node] = make_int2(e, e + v);
            dinv[node] = dv;
            xs[node] = make_float4(x[3*node]*dv, x[3*node+1]*dv, x[3*node+2]*dv, dv);
        }
        hist[t] = e;                           // repurpose as fill cursor
    }
    __syncthreads();
    for (int i = pbeg + t; i < pend; i += 512) {
        u32 p = pairs[i];
        int pos = atomicAdd(&hist[p >> 17], 1);
        csr_src[pos] = (int)(p & 0x1FFFFu);
    }
}

// ------ fused layer-1 aggregate + expand + layer-2 matmul (128 nodes/block) -
// Agg: 2 threads/node, alternating 8-edge volleys; partials staged in LDS
// aliased onto hT rows 0..7 (dead until phase-1 reads complete, barrier-
// ordered). GEMM: each thread 8 nodes x 4 features; per k-step 3x ds_read_b128
// feeds 32 FMAs.

#define MMN 128
__global__ void agg_mm2(const float4* __restrict__ xs, const int* __restrict__ csr_src,
                        const int2* __restrict__ off2,
                        const float* __restrict__ W1, const float* __restrict__ b1,
                        const float* __restrict__ W2,
                        u16* __restrict__ A16, int n) {
    __shared__ float w[HID * HID];     // 16 KB, w[k*64+f]
    __shared__ float hT[HID][MMN];     // 32 KB, hT[k][node_local]
    __shared__ float dd[MMN];          // dst dinv per node
    __shared__ float w1s[4 * HID];     // W1 rows 0..2 + b1
    float4* paggs = (float4*)&hT[0][0];   // [128][2] partial sums, 4 KB alias
    int t = threadIdx.x;               // 256 threads

    // stage W2 (float4-vectorized) + W1/b1; in flight while gathers issue
    {
        float4* w4p = (float4*)w;
        const float4* W2v = (const float4*)W2;
        #pragma unroll
        for (int i = 0; i < 4; ++i) w4p[t + 256 * i] = W2v[t + 256 * i];
    }
    if (t < HID) {
        w1s[t]           = W1[t];
        w1s[HID + t]     = W1[HID + t];
        w1s[2 * HID + t] = W1[2 * HID + t];
        w1s[3 * HID + t] = b1[t];
    }

    int base = blockIdx.x * MMN;
    int nl = t >> 1, half = t & 1;     // 2 threads per node
    int node = base + nl;
    float a0 = 0.f, a1 = 0.f, a2 = 0.f, dv = 0.f;
    if (node < n) {
        int2 be = off2[node];
        int beg = be.x, end = be.y, e1 = end - 1;
        if (half == 0) {
            float4 self = xs[node];
            a0 = self.x; a1 = self.y; a2 = self.z; dv = self.w;
            dd[nl] = dv;
        }
        for (int k = beg + half * 8; k < end; k += 16) {
            int idx[8]; float4 v[8];
            #pragma unroll
            for (int j = 0; j < 8; ++j) idx[j] = csr_src[min(k + j, e1)];
            #pragma unroll
            for (int j = 0; j < 8; ++j) v[j] = xs[idx[j]];
            #pragma unroll
            for (int j = 0; j < 8; ++j) {
                if (k + j < end) { a0 += v[j].x; a1 += v[j].y; a2 += v[j].z; }
            }
        }
    } else if (half == 0) {
        dd[nl] = 0.f;
    }
    paggs[(nl << 1) | half] = make_float4(a0, a1, a2, dv);
    __syncthreads();

    // phase 1: combine partials, expand h1 = relu((agg @ W1 + b1) * dinv)
    // into transposed LDS. thread t covers node nl1, features f=(t>>7)+2s.
    int nl1 = t & 127;
    float4 pa = paggs[nl1 * 2], pb = paggs[nl1 * 2 + 1];
    float4 a = make_float4(pa.x + pb.x, pa.y + pb.y, pa.z + pb.z, pa.w + pb.w);
    __syncthreads();                   // all paggs reads done before hT writes
    int fbase = t >> 7;                // 0 or 1
    #pragma unroll
    for (int s = 0; s < 32; ++s) {
        int f = fbase + 2 * s;
        float v = (a.x * w1s[f] + a.y * w1s[HID + f] + a.z * w1s[2 * HID + f]) * a.w
                  + w1s[3 * HID + f];
        hT[f][nl1] = v > 0.f ? v : 0.f;    // invalid nodes: garbage col, never stored
    }
    __syncthreads();

    // phase 2: GEMM. fq = feature quad (0..15), oct = node octet (0..15).
    int fq = t & 15, oct = t >> 4;
    int nb = oct * 8;
    float acc[8][4];
    #pragma unroll
    for (int j = 0; j < 8; ++j)
        #pragma unroll
        for (int q = 0; q < 4; ++q) acc[j][q] = 0.f;

    #pragma unroll 4
    for (int k = 0; k < HID; ++k) {
        float4 w4 = *(const float4*)&w[k * HID + fq * 4];
        float4 h0 = *(const float4*)&hT[k][nb];
        float4 h1 = *(const float4*)&hT[k][nb + 4];
        float hv[8] = { h0.x, h0.y, h0.z, h0.w, h1.x, h1.y, h1.z, h1.w };
        #pragma unroll
        for (int j = 0; j < 8; ++j) {
            acc[j][0] += hv[j] * w4.x;
            acc[j][1] += hv[j] * w4.y;
            acc[j][2] += hv[j] * w4.z;
            acc[j][3] += hv[j] * w4.w;
        }
    }

    #pragma unroll
    for (int j = 0; j < 8; ++j) {
        int nodej = base + nb + j;
        if (nodej < n) {
            float dj = dd[nb + j];
            u64 outp = (u64)f2bf(acc[j][0] * dj)
                     | ((u64)f2bf(acc[j][1] * dj) << 16)
                     | ((u64)f2bf(acc[j][2] * dj) << 32)
                     | ((u64)f2bf(acc[j][3] * dj) << 48);
            *(u64*)(A16 + ((size_t)nodej << 6) + (fq << 2)) = outp;
        }
    }
}

// -------- layer-2 gather: 1 node/wave, 32-row volleys, 4-row loads ----------
// Each load inst covers 4 rows (64 lanes x 8B = 512B): row slot = lane>>4,
// feature quad = lane&15. Accumulators 4-way replicated across row slots,
// combined once per node via shfl_xor(16/32). Self row seeds replica 0.
// Wave processes 4 consecutive nodes serially (sequential csr index loads).
// Barrier-free; wave-uniform control flow; waves retire independently.

__global__ void gather_nodes(const u16* __restrict__ A16, const float* __restrict__ dinv,
                             const int* __restrict__ csr_src, const int2* __restrict__ off2,
                             const float* __restrict__ bias,
                             u16* __restrict__ H16, int n) {
    int t = threadIdx.x;               // 256
    int wv = t >> 6;                   // wave 0..3
    int l  = t & 63;                   // lane
    int m  = l & 15;                   // feature quad: features 4m..4m+3
    int rs = l >> 4;                   // row slot / replica 0..3
    const char* Ab = (const char*)A16;
    u32 laneoff = (u32)(m << 3);       // byte offset of my quad within a row
    float4 bb = *(const float4*)(bias + (m << 2));
    int nbase = blockIdx.x * 16 + wv * 4;

    for (int it = 0; it < 4; ++it) {
        int node = nbase + it;
        if (node >= n) break;          // wave-uniform (node monotone in it)
        int2 be = off2[node];
        int beg = be.x, end = be.y;
        // self row -> replica 0 only (others start at 0)
        u64 srow = (rs == 0) ? *(const u64*)(Ab + (((size_t)node << 7) | laneoff)) : 0ull;
        u32 slo = (u32)srow, shi = (u32)(srow >> 32);
        float acc0 = bf2f((u16)(slo & 0xffffu));
        float acc1 = bf2f((u16)(slo >> 16));
        float acc2 = bf2f((u16)(shi & 0xffffu));
        float acc3 = bf2f((u16)(shi >> 16));
        for (int k = beg; k < end; k += 32) {
            int myIdx = n;             // pad -> zero row
            if (l < 32 && k + l < end) myIdx = csr_src[k + l];
            int ss[8]; u64 rows[8];
            #pragma unroll
            for (int j = 0; j < 8; ++j)
                ss[j] = __shfl(myIdx, (j << 2) + rs, 64);   // row k + j*4 + rs
            #pragma unroll
            for (int j = 0; j < 8; ++j)
                rows[j] = *(const u64*)(Ab + (((u32)ss[j] << 7) | laneoff));
            #pragma unroll
            for (int j = 0; j < 8; ++j) {
                u32 lo = (u32)rows[j], hi = (u32)(rows[j] >> 32);
                acc0 += bf2f((u16)(lo & 0xffffu));
                acc1 += bf2f((u16)(lo >> 16));
                acc2 += bf2f((u16)(hi & 0xffffu));
                acc3 += bf2f((u16)(hi >> 16));
            }
        }
        // combine the 4 replicas (lanes m, m+16, m+32, m+48)
        acc0 += __shfl_xor(acc0, 16, 64); acc0 += __shfl_xor(acc0, 32, 64);
        acc1 += __shfl_xor(acc1, 16, 64); acc1 += __shfl_xor(acc1, 32, 64);
        acc2 += __shfl_xor(acc2, 16, 64); acc2 += __shfl_xor(acc2, 32, 64);
        acc3 += __shfl_xor(acc3, 16, 64); acc3 += __shfl_xor(acc3, 32, 64);
        if (rs == 0) {
            float ddv = dinv[node];
            float v0 = fmaxf(acc0 * ddv + bb.x, 0.0f);
            float v1 = fmaxf(acc1 * ddv + bb.y, 0.0f);
            float v2 = fmaxf(acc2 * ddv + bb.z, 0.0f);
            float v3 = fmaxf(acc3 * ddv + bb.w, 0.0f);
            u64 outp = (u64)f2bf(v0) | ((u64)f2bf(v1) << 16)
                     | ((u64)f2bf(v2) << 32) | ((u64)f2bf(v3) << 48);
            *(u64*)(H16 + ((size_t)node << 6) + (m << 2)) = outp;
        }
    }
}

// ---------------- global mean pool: one block per graph, no atomics ---------

__global__ void pool_graph(const u16* __restrict__ H16, const int* __restrict__ gstart,
                           float* __restrict__ out, int n) {
    int g = blockIdx.x;
    int t = threadIdx.x;
    int lo = gstart[g];
    int hi = gstart[g + 1];
    int cntN = hi - lo;
    int sid = t >> 4;                  // stream 0..15
    int m = t & 15;                    // feature quad
    float a0 = 0.f, a1 = 0.f, a2 = 0.f, a3 = 0.f;
    int i = lo + sid;
    for (; i + 16 < hi; i += 32) {     // unroll x2 for MLP
        u64 r0 = *(const u64*)(H16 + ((size_t)i << 6) + (m << 2));
        u64 r1 = *(const u64*)(H16 + ((size_t)(i + 16) << 6) + (m << 2));
        u32 l0 = (u32)r0, h0 = (u32)(r0 >> 32);
        u32 l1 = (u32)r1, h1 = (u32)(r1 >> 32);
        a0 += bf2f((u16)(l0 & 0xffffu)) + bf2f((u16)(l1 & 0xffffu));
        a1 += bf2f((u16)(l0 >> 16))     + bf2f((u16)(l1 >> 16));
        a2 += bf2f((u16)(h0 & 0xffffu)) + bf2f((u16)(h1 & 0xffffu));
        a3 += bf2f((u16)(h0 >> 16))     + bf2f((u16)(h1 >> 16));
    }
    if (i < hi) {
        u64 r0 = *(const u64*)(H16 + ((size_t)i << 6) + (m << 2));
        u32 l0 = (u32)r0, h0 = (u32)(r0 >> 32);
        a0 += bf2f((u16)(l0 & 0xffffu));
        a1 += bf2f((u16)(l0 >> 16));
        a2 += bf2f((u16)(h0 & 0xffffu));
        a3 += bf2f((u16)(h0 >> 16));
    }
    a0 += __shfl_xor(a0, 16, 64); a0 += __shfl_xor(a0, 32, 64);
    a1 += __shfl_xor(a1, 16, 64); a1 += __shfl_xor(a1, 32, 64);
    a2 += __shfl_xor(a2, 16, 64); a2 += __shfl_xor(a2, 32, 64);
    a3 += __shfl_xor(a3, 16, 64); a3 += __shfl_xor(a3, 32, 64);
    __shared__ float smf[4 * HID];
    int wave = t >> 6, lane = t & 63;
    if (lane < 16) {
        smf[wave * HID + 4 * lane + 0] = a0;
        smf[wave * HID + 4 * lane + 1] = a1;
        smf[wave * HID + 4 * lane + 2] = a2;
        smf[wave * HID + 4 * lane + 3] = a3;
    }
    __syncthreads();
    if (t < HID) {
        float s = smf[t] + smf[HID + t] + smf[2 * HID + t] + smf[3 * HID + t];
        out[(size_t)g * HID + t] = s / fmaxf((float)cntN, 1.0f);
    }
}

// ---------------- launcher ----------------

extern "C" void kernel_launch(void* const* d_in, const int* in_sizes, int n_in,
                              void* d_out, int out_size, void* d_ws, size_t ws_size,
                              hipStream_t stream) {
    const float* x  = (const float*)d_in[0];
    const float* W1 = (const float*)d_in[1];
    const float* b1 = (const float*)d_in[2];
    const float* W2 = (const float*)d_in[3];
    const float* b2 = (const float*)d_in[4];
    const int*   ei = (const int*)d_in[5];
    const int*   batch = (const int*)d_in[6];

    const int n  = in_sizes[0] / 3;   // 100000
    const int nE = in_sizes[5] / 2;   // 1000000
    const int* src = ei;
    const int* dst = ei + nE;
    const int nbuck = (n + ((1 << BSHIFT) - 1)) >> BSHIFT;   // 391
    const int nGraphs = out_size / HID;                      // 512

    // workspace layout
    char* p = (char*)d_ws;
    int*    gcursor = (int*)p;                p += 2048;
    int*    gstart  = (int*)p;                p += 4096;   // 513 ints (padded)
    int*    csr_src = (int*)p;                p += (size_t)nbuck * CAP * 4;  // 5.1 MB
    int2*   off2    = (int2*)p;               p += (size_t)n * 8;
    float*  dinv    = (float*)p;              p += (size_t)n * 4;
    float4* xs      = (float4*)p;             p += (size_t)n * 16;
    u16*    A16     = (u16*)p;                p += (size_t)(n + 1) * HID * 2; // +pad row
    u16*    H2      = (u16*)p;                p += (size_t)n * HID * 2;
    u32*    pairs   = (u32*)A16;              // 5.1 MB alias; dead before agg_mm2

    const int gridE2   = (nE + EPB - 1) / EPB;           // 245
    const int gridMM2  = (n + MMN - 1) / MMN;            // 782
    const int gridGath = (n + 15) / 16;                  // 6250
    const int BT = 256;

    // zero bucket cursors (2 KB), then bin + csr build (csr also computes
    // gstart in block 0)
    hipMemsetAsync(gcursor, 0, 2048, stream);
    bin_pairs<<<gridE2, 512, 0, stream>>>(src, dst, gcursor, pairs, nE, nbuck);
    build_csr<<<nbuck, 512, 0, stream>>>(pairs, gcursor, csr_src, off2, dinv, x, xs,
                                         A16, batch, gstart, nGraphs, n);

    // fused layer-1 aggregate + expand + layer-2 matmul
    agg_mm2<<<gridMM2, BT, 0, stream>>>(xs, csr_src, off2, W1, b1, W2, A16, n);

    // layer-2 gather (1 node/wave, 32-row volleys)
    gather_nodes<<<gridGath, BT, 0, stream>>>(A16, dinv, csr_src, off2, b2, H2, n);

    // pool
    pool_graph<<<nGraphs, BT, 0, stream>>>(H2, gstart, (float*)d_out, n);
}

// Round 9
// 153.963 us; speedup vs baseline: 1.1119x; 1.1119x over previous
//
#include <hip/hip_runtime.h>

#define HID 64
#define N_GRAPHS_C 512
#define BSHIFT 8          // 256 nodes per coarse bucket
#define NBUCK_MAX 512
#define CAP 3264          // bucket capacity (mean 2560 + ~12 sigma)
#define EPB 4096          // edges per block in bin pass (245 blocks; 2048 was -3us worse, r6)
#define EPT (EPB / 512)   // edges per thread in bin pass (8)

typedef unsigned short u16;
typedef unsigned int u32;
typedef unsigned long long u64;

__device__ __forceinline__ float bf2f(u16 u) {
    union { u32 i; float f; } v; v.i = ((u32)u) << 16; return v.f;
}
__device__ __forceinline__ u16 f2bf(float f) {
    union { float f; u32 i; } v; v.f = f;
    u32 x = v.i;
    return (u16)((x + 0x7fffu + ((x >> 16) & 1u)) >> 16);  // RNE
}

__device__ __forceinline__ int lower_bound(const int* __restrict__ a, int n, int key) {
    int lo = 0, hi = n;
    while (lo < hi) {
        int mid = (lo + hi) >> 1;
        if (a[mid] < key) lo = mid + 1; else hi = mid;
    }
    return lo;
}

// ---------------- binning: packed u32 pairs, 512-thread blocks --------------
// pack = (local_dst << 17) | src   (local_dst < 256 -> 8 bits, src < 131072)
// gcursor pre-zeroed by hipMemsetAsync.

__global__ void bin_pairs(const int* __restrict__ src, const int* __restrict__ dst,
                          int* __restrict__ gcursor, u32* __restrict__ pairs,
                          int nE, int nbuck) {
    __shared__ int lh[NBUCK_MAX];
    __shared__ int lbase[NBUCK_MAX];
    int t = threadIdx.x;                       // 0..511
    lh[t] = 0;
    __syncthreads();
    int base = blockIdx.x * EPB;
    u32 pk[EPT]; int rj[EPT], bj[EPT];
    #pragma unroll
    for (int j = 0; j < EPT; ++j) {
        int e = base + j * 512 + t;
        if (e < nE) {
            int s = src[e], d = dst[e];
            bj[j] = d >> BSHIFT;
            pk[j] = ((u32)(d & 255) << 17) | (u32)s;
            rj[j] = atomicAdd(&lh[bj[j]], 1);
        } else {
            bj[j] = -1;
        }
    }
    __syncthreads();
    if (t < nbuck) lbase[t] = (lh[t] > 0) ? atomicAdd(&gcursor[t], lh[t]) : 0;
    __syncthreads();
    #pragma unroll
    for (int j = 0; j < EPT; ++j) {
        if (bj[j] >= 0) {
            int pos = bj[j] * CAP + lbase[bj[j]] + rj[j];
            pairs[pos] = pk[j];
        }
    }
}

// One block per bucket (512 thr): LDS histogram, LDS scan (first 256 thr) ->
// (beg,end) + dinv + xs, then LDS-cursor csr fill. Block 0 also computes
// gstart (one binary search per thread) and zeroes the A16 pad row.
__global__ void build_csr(const u32* __restrict__ pairs, const int* __restrict__ gcursor,
                          int* __restrict__ csr_src, int2* __restrict__ off2,
                          float* __restrict__ dinv, const float* __restrict__ x,
                          float4* __restrict__ xs, u16* __restrict__ A16,
                          const int* __restrict__ batch, int* __restrict__ gstart,
                          int nGraphs, int n) {
    __shared__ int hist[256];
    __shared__ int tmp[256];
    int t = threadIdx.x;                       // 0..511
    int b = blockIdx.x;
    int pbeg = b * CAP;
    int pend = pbeg + gcursor[b];
    if (t < 256) hist[t] = 0;
    if (b == 0 && t < 32) ((u32*)(A16 + (size_t)n * HID))[t] = 0;  // zero pad row
    if (b == 0) {                              // gstart: 513 searches, 1/thread
        for (int g = t; g <= nGraphs; g += 512)
            gstart[g] = lower_bound(batch, n, g);
    }
    __syncthreads();
    for (int i = pbeg + t; i < pend; i += 512)
        atomicAdd(&hist[pairs[i] >> 17], 1);
    __syncthreads();
    int v = 0;
    if (t < 256) { v = hist[t]; tmp[t] = v; }
    __syncthreads();
    for (int d = 1; d < 256; d <<= 1) {
        int add = (t >= d && t < 256) ? tmp[t - d] : 0;
        __syncthreads();
        if (t < 256) tmp[t] += add;
        __syncthreads();
    }
    if (t < 256) {
        int e = pbeg + tmp[t] - v;             // exclusive
        int node = (b << BSHIFT) + t;
        if (node < n) {
            float dv = rsqrtf((float)(v + 1));
            off2[node] = make_int2(e, e + v);
            dinv[node] = dv;
            xs[node] = make_float4(x[3*node]*dv, x[3*node+1]*dv, x[3*node+2]*dv, dv);
        }
        hist[t] = e;                           // repurpose as fill cursor
    }
    __syncthreads();
    for (int i = pbeg + t; i < pend; i += 512) {
        u32 p = pairs[i];
        int pos = atomicAdd(&hist[p >> 17], 1);
        csr_src[pos] = (int)(p & 0x1FFFFu);
    }
}

// ------ fused layer-1 aggregate + expand + layer-2 matmul (128 nodes/block) -
// Agg: 2 threads/node, alternating 8-edge volleys; partials staged in LDS
// aliased onto hT rows 0..7 (dead until phase-1 reads complete, barrier-
// ordered). GEMM: each thread 8 nodes x 4 features; per k-step 3x ds_read_b128
// feeds 32 FMAs.

#define MMN 128
__global__ void agg_mm2(const float4* __restrict__ xs, const int* __restrict__ csr_src,
                        const int2* __restrict__ off2,
                        const float* __restrict__ W1, const float* __restrict__ b1,
                        const float* __restrict__ W2,
                        u16* __restrict__ A16, int n) {
    __shared__ float w[HID * HID];     // 16 KB, w[k*64+f]
    __shared__ float hT[HID][MMN];     // 32 KB, hT[k][node_local]
    __shared__ float dd[MMN];          // dst dinv per node
    __shared__ float w1s[4 * HID];     // W1 rows 0..2 + b1
    float4* paggs = (float4*)&hT[0][0];   // [128][2] partial sums, 4 KB alias
    int t = threadIdx.x;               // 256 threads

    // stage W2 (float4-vectorized) + W1/b1; in flight while gathers issue
    {
        float4* w4p = (float4*)w;
        const float4* W2v = (const float4*)W2;
        #pragma unroll
        for (int i = 0; i < 4; ++i) w4p[t + 256 * i] = W2v[t + 256 * i];
    }
    if (t < HID) {
        w1s[t]           = W1[t];
        w1s[HID + t]     = W1[HID + t];
        w1s[2 * HID + t] = W1[2 * HID + t];
        w1s[3 * HID + t] = b1[t];
    }

    int base = blockIdx.x * MMN;
    int nl = t >> 1, half = t & 1;     // 2 threads per node
    int node = base + nl;
    float a0 = 0.f, a1 = 0.f, a2 = 0.f, dv = 0.f;
    if (node < n) {
        int2 be = off2[node];
        int beg = be.x, end = be.y, e1 = end - 1;
        if (half == 0) {
            float4 self = xs[node];
            a0 = self.x; a1 = self.y; a2 = self.z; dv = self.w;
            dd[nl] = dv;
        }
        for (int k = beg + half * 8; k < end; k += 16) {
            int idx[8]; float4 v[8];
            #pragma unroll
            for (int j = 0; j < 8; ++j) idx[j] = csr_src[min(k + j, e1)];
            #pragma unroll
            for (int j = 0; j < 8; ++j) v[j] = xs[idx[j]];
            #pragma unroll
            for (int j = 0; j < 8; ++j) {
                if (k + j < end) { a0 += v[j].x; a1 += v[j].y; a2 += v[j].z; }
            }
        }
    } else if (half == 0) {
        dd[nl] = 0.f;
    }
    paggs[(nl << 1) | half] = make_float4(a0, a1, a2, dv);
    __syncthreads();

    // phase 1: combine partials, expand h1 = relu((agg @ W1 + b1) * dinv)
    // into transposed LDS. thread t covers node nl1, features f=(t>>7)+2s.
    int nl1 = t & 127;
    float4 pa = paggs[nl1 * 2], pb = paggs[nl1 * 2 + 1];
    float4 a = make_float4(pa.x + pb.x, pa.y + pb.y, pa.z + pb.z, pa.w + pb.w);
    __syncthreads();                   // all paggs reads done before hT writes
    int fbase = t >> 7;                // 0 or 1
    #pragma unroll
    for (int s = 0; s < 32; ++s) {
        int f = fbase + 2 * s;
        float v = (a.x * w1s[f] + a.y * w1s[HID + f] + a.z * w1s[2 * HID + f]) * a.w
                  + w1s[3 * HID + f];
        hT[f][nl1] = v > 0.f ? v : 0.f;    // invalid nodes: garbage col, never stored
    }
    __syncthreads();

    // phase 2: GEMM. fq = feature quad (0..15), oct = node octet (0..15).
    int fq = t & 15, oct = t >> 4;
    int nb = oct * 8;
    float acc[8][4];
    #pragma unroll
    for (int j = 0; j < 8; ++j)
        #pragma unroll
        for (int q = 0; q < 4; ++q) acc[j][q] = 0.f;

    #pragma unroll 4
    for (int k = 0; k < HID; ++k) {
        float4 w4 = *(const float4*)&w[k * HID + fq * 4];
        float4 h0 = *(const float4*)&hT[k][nb];
        float4 h1 = *(const float4*)&hT[k][nb + 4];
        float hv[8] = { h0.x, h0.y, h0.z, h0.w, h1.x, h1.y, h1.z, h1.w };
        #pragma unroll
        for (int j = 0; j < 8; ++j) {
            acc[j][0] += hv[j] * w4.x;
            acc[j][1] += hv[j] * w4.y;
            acc[j][2] += hv[j] * w4.z;
            acc[j][3] += hv[j] * w4.w;
        }
    }

    #pragma unroll
    for (int j = 0; j < 8; ++j) {
        int nodej = base + nb + j;
        if (nodej < n) {
            float dj = dd[nb + j];
            u64 outp = (u64)f2bf(acc[j][0] * dj)
                     | ((u64)f2bf(acc[j][1] * dj) << 16)
                     | ((u64)f2bf(acc[j][2] * dj) << 32)
                     | ((u64)f2bf(acc[j][3] * dj) << 48);
            *(u64*)(A16 + ((size_t)nodej << 6) + (fq << 2)) = outp;
        }
    }
}

// ---------------- layer-2 gather: 4 nodes/wave, u64 lanes, volley of 8 ------
// Barrier-free; quarter-uniform early exit; waves retire independently.
// (r8's 1-node/wave 32-row variant was +16us: 32-row volley quantum wastes
//  ~2x loads at Poisson(10) degrees and serializes inter-node MLP.)

__global__ void gather_nodes(const u16* __restrict__ A16, const float* __restrict__ dinv,
                             const int* __restrict__ csr_src, const int2* __restrict__ off2,
                             const float* __restrict__ bias,
                             u16* __restrict__ H16, int n) {
    int t = threadIdx.x;
    int waveq = t >> 4;                // 0..15: quarter index within block
    int m = t & 15;                    // feature quad: features 4m..4m+3
    int qbase = t & 48;                // base lane of my quarter within the wave
    int node = blockIdx.x * 16 + waveq;
    if (node >= n) return;             // quarter-uniform exit, no barriers below
    int2 be = off2[node];
    int beg = be.x, end = be.y;
    u64 selfrow = *(const u64*)(A16 + ((size_t)node << 6) + (m << 2));
    u32 slo = (u32)selfrow, shi = (u32)(selfrow >> 32);
    float acc0 = bf2f((u16)(slo & 0xffffu));
    float acc1 = bf2f((u16)(slo >> 16));
    float acc2 = bf2f((u16)(shi & 0xffffu));
    float acc3 = bf2f((u16)(shi >> 16));
    const char* Ab = (const char*)A16;
    u32 laneoff = (u32)(m << 3);       // byte offset of my quad within a row
    for (int k = beg; k < end; k += 8) {
        int lim = min(end - k, 8);
        int myIdx = (m < lim) ? csr_src[k + m] : n;   // pad -> zero row
        int ss[8]; u64 rows[8];
        #pragma unroll
        for (int j = 0; j < 8; ++j)
            ss[j] = __shfl(myIdx, qbase + j, 64);
        #pragma unroll
        for (int j = 0; j < 8; ++j)
            rows[j] = *(const u64*)(Ab + (((u32)ss[j] << 7) | laneoff));
        #pragma unroll
        for (int j = 0; j < 8; ++j) {
            u32 lo = (u32)rows[j], hi = (u32)(rows[j] >> 32);
            acc0 += bf2f((u16)(lo & 0xffffu));
            acc1 += bf2f((u16)(lo >> 16));
            acc2 += bf2f((u16)(hi & 0xffffu));
            acc3 += bf2f((u16)(hi >> 16));
        }
    }
    float ddv = dinv[node];
    float4 bb = *(const float4*)(bias + (m << 2));
    float v0 = fmaxf(acc0 * ddv + bb.x, 0.0f);
    float v1 = fmaxf(acc1 * ddv + bb.y, 0.0f);
    float v2 = fmaxf(acc2 * ddv + bb.z, 0.0f);
    float v3 = fmaxf(acc3 * ddv + bb.w, 0.0f);
    u64 outp = (u64)f2bf(v0) | ((u64)f2bf(v1) << 16)
             | ((u64)f2bf(v2) << 32) | ((u64)f2bf(v3) << 48);
    *(u64*)(H16 + ((size_t)node << 6) + (m << 2)) = outp;
}

// ---------------- global mean pool: one block per graph, no atomics ---------

__global__ void pool_graph(const u16* __restrict__ H16, const int* __restrict__ gstart,
                           float* __restrict__ out, int n) {
    int g = blockIdx.x;
    int t = threadIdx.x;
    int lo = gstart[g];
    int hi = gstart[g + 1];
    int cntN = hi - lo;
    int sid = t >> 4;                  // stream 0..15
    int m = t & 15;                    // feature quad
    float a0 = 0.f, a1 = 0.f, a2 = 0.f, a3 = 0.f;
    int i = lo + sid;
    for (; i + 16 < hi; i += 32) {     // unroll x2 for MLP
        u64 r0 = *(const u64*)(H16 + ((size_t)i << 6) + (m << 2));
        u64 r1 = *(const u64*)(H16 + ((size_t)(i + 16) << 6) + (m << 2));
        u32 l0 = (u32)r0, h0 = (u32)(r0 >> 32);
        u32 l1 = (u32)r1, h1 = (u32)(r1 >> 32);
        a0 += bf2f((u16)(l0 & 0xffffu)) + bf2f((u16)(l1 & 0xffffu));
        a1 += bf2f((u16)(l0 >> 16))     + bf2f((u16)(l1 >> 16));
        a2 += bf2f((u16)(h0 & 0xffffu)) + bf2f((u16)(h1 & 0xffffu));
        a3 += bf2f((u16)(h0 >> 16))     + bf2f((u16)(h1 >> 16));
    }
    if (i < hi) {
        u64 r0 = *(const u64*)(H16 + ((size_t)i << 6) + (m << 2));
        u32 l0 = (u32)r0, h0 = (u32)(r0 >> 32);
        a0 += bf2f((u16)(l0 & 0xffffu));
        a1 += bf2f((u16)(l0 >> 16));
        a2 += bf2f((u16)(h0 & 0xffffu));
        a3 += bf2f((u16)(h0 >> 16));
    }
    a0 += __shfl_xor(a0, 16, 64); a0 += __shfl_xor(a0, 32, 64);
    a1 += __shfl_xor(a1, 16, 64); a1 += __shfl_xor(a1, 32, 64);
    a2 += __shfl_xor(a2, 16, 64); a2 += __shfl_xor(a2, 32, 64);
    a3 += __shfl_xor(a3, 16, 64); a3 += __shfl_xor(a3, 32, 64);
    __shared__ float smf[4 * HID];
    int wave = t >> 6, lane = t & 63;
    if (lane < 16) {
        smf[wave * HID + 4 * lane + 0] = a0;
        smf[wave * HID + 4 * lane + 1] = a1;
        smf[wave * HID + 4 * lane + 2] = a2;
        smf[wave * HID + 4 * lane + 3] = a3;
    }
    __syncthreads();
    if (t < HID) {
        float s = smf[t] + smf[HID + t] + smf[2 * HID + t] + smf[3 * HID + t];
        out[(size_t)g * HID + t] = s / fmaxf((float)cntN, 1.0f);
    }
}

// ---------------- launcher ----------------

extern "C" void kernel_launch(void* const* d_in, const int* in_sizes, int n_in,
                              void* d_out, int out_size, void* d_ws, size_t ws_size,
                              hipStream_t stream) {
    const float* x  = (const float*)d_in[0];
    const float* W1 = (const float*)d_in[1];
    const float* b1 = (const float*)d_in[2];
    const float* W2 = (const float*)d_in[3];
    const float* b2 = (const float*)d_in[4];
    const int*   ei = (const int*)d_in[5];
    const int*   batch = (const int*)d_in[6];

    const int n  = in_sizes[0] / 3;   // 100000
    const int nE = in_sizes[5] / 2;   // 1000000
    const int* src = ei;
    const int* dst = ei + nE;
    const int nbuck = (n + ((1 << BSHIFT) - 1)) >> BSHIFT;   // 391
    const int nGraphs = out_size / HID;                      // 512

    // workspace layout
    char* p = (char*)d_ws;
    int*    gcursor = (int*)p;                p += 2048;
    int*    gstart  = (int*)p;                p += 4096;   // 513 ints (padded)
    int*    csr_src = (int*)p;                p += (size_t)nbuck * CAP * 4;  // 5.1 MB
    int2*   off2    = (int2*)p;               p += (size_t)n * 8;
    float*  dinv    = (float*)p;              p += (size_t)n * 4;
    float4* xs      = (float4*)p;             p += (size_t)n * 16;
    u16*    A16     = (u16*)p;                p += (size_t)(n + 1) * HID * 2; // +pad row
    u16*    H2      = (u16*)p;                p += (size_t)n * HID * 2;
    u32*    pairs   = (u32*)A16;              // 5.1 MB alias; dead before agg_mm2

    const int gridE2   = (nE + EPB - 1) / EPB;           // 245
    const int gridMM2  = (n + MMN - 1) / MMN;            // 782
    const int gridGath = (n + 15) / 16;                  // 6250
    const int BT = 256;

    // zero bucket cursors (2 KB), then bin + csr build (csr also computes
    // gstart in block 0)
    hipMemsetAsync(gcursor, 0, 2048, stream);
    bin_pairs<<<gridE2, 512, 0, stream>>>(src, dst, gcursor, pairs, nE, nbuck);
    build_csr<<<nbuck, 512, 0, stream>>>(pairs, gcursor, csr_src, off2, dinv, x, xs,
                                         A16, batch, gstart, nGraphs, n);

    // fused layer-1 aggregate + expand + layer-2 matmul
    agg_mm2<<<gridMM2, BT, 0, stream>>>(xs, csr_src, off2, W1, b1, W2, A16, n);

    // layer-2 gather
    gather_nodes<<<gridGath, BT, 0, stream>>>(A16, dinv, csr_src, off2, b2, H2, n);

    // pool
    pool_graph<<<nGraphs, BT, 0, stream>>>(H2, gstart, (float*)d_out, n);
}